// Round 6
// baseline (652.261 us; speedup 1.0000x reference)
//
#include <hip/hip_runtime.h>
#include <math.h>

// 31x31 depthwise Gaussian (sigma=3) == separable 25-tap Gaussian applied
// twice (outer 3 taps of the 31 are exactly zero). Reflection effectively at
// radius 12 (reference pads 15 but the outer taps are zero).
//
// R8 (resubmit after infra failure): R5 vertical-first structure + z-batching.
//   - R5 (81.7us): occupancy stuck at ~12 waves/CU (~3 blocks) though LDS/
//     VGPR/slots allow 8 blocks/CU. Cross-round data (R3/R5/R6/R7) shows a
//     sustained ~150 workgroup/us launch rate with ~5us block lifetimes ->
//     residency is LAUNCH-limited, not resource-limited.
//   - R6/R7 (reverted): tile growth pushed VGPR over the 64 cliff (68-72).
//   - R8: identical per-task shape as R5 (VGPR 52), but each block loops
//     over 4 z-slices (grid.z=24, z = bz + 24*zi). 3072 blocks x ~20us
//     lifetime -> launch rate needed ~90/us -> residency can fill the
//     8-block cap. 24%3==0 -> ch invariant -> kk loaded once.
//     __launch_bounds__(256,8) pins VGPR<=64 so the cliff is compile-time.

#define IW 512
#define IH 512
#define RAD 12
#define TW 64                 // output tile width
#define TH 32                 // output tile height
#define MCOLS 96              // staged mid cols: c0-16 .. c0+79 (need c0-12..c0+75)
#define MSTRIDE 97            // 97%32==1 -> conflict-free / exact-2-way patterns
#define NTASKV (MCOLS * 4)    // 384 vertical tasks (8 output rows each)
#define ZB 4                  // z-slices per block
#define ZGRID (96 / ZB)       // 24; 24%3==0 keeps channel fixed per block

__global__ __launch_bounds__(256, 8)
void gauss_blur_sep3_kernel(const float* __restrict__ x,
                            const float* __restrict__ wgt,
                            float* __restrict__ out)
{
    __shared__ float mid[TH * MSTRIDE];   // 3104 floats = 12416 B

    const int tid = threadIdx.x;
    const int ch  = blockIdx.z % 3;       // invariant across the z-loop

    // 1D kernel from 2D weight (uniform per block -> scalar loads):
    // k1[t] = w2d[15][3+t] / sqrt(w2d[15][15]), symmetric, t=0..12 held.
    float kk[13];
    {
        const float* __restrict__ wp = wgt + ch * 961 + 15 * 31;
        const float inv = 1.0f / sqrtf(wp[15]);
#pragma unroll
        for (int t = 0; t < 13; ++t) kk[t] = wp[3 + t] * inv;
    }

    const int r0g = blockIdx.y * TH;
    const int c0g = blockIdx.x * TW;
    const int g   = tid & 7;              // phase-H column group
    const int r   = tid >> 3;             // phase-H row

#pragma unroll 1
    for (int zi = 0; zi < ZB; ++zi) {
        const int z = blockIdx.z + ZGRID * zi;
        const float* __restrict__ src = x + (size_t)z * (IW * IH);

        if (zi) __syncthreads();          // mid reused: wait for prev phase H

        // ---------- phase V: vertical pass, global -> LDS mid ---------------
        // task (cp, rb): column c0g-16+cp (reflected), output rows
        // r0g+8rb..+7, input rows r0g+8rb-12 .. +19 (32 coalesced loads).
#pragma unroll 1
        for (int i = 0; i < 2; ++i) {
            const int task = tid + i * 256;
            if (i == 0 || task < NTASKV) {    // i==1: tid<128, wave-uniform
                const int rb = task / MCOLS;
                const int cp = task - rb * MCOLS;
                int gc = c0g - 16 + cp;
                gc = gc < 0 ? -gc : (gc >= IW ? 2 * IW - 2 - gc : gc);
                const int first = r0g + 8 * rb - RAD;

                float v[32];
                if (first >= 0 && first + 31 < IH) {
                    const float* __restrict__ p = src + (size_t)first * IW + gc;
#pragma unroll
                    for (int j = 0; j < 32; ++j) v[j] = p[(size_t)j * IW];
                } else {
#pragma unroll
                    for (int j = 0; j < 32; ++j) {
                        int gr = first + j;
                        gr = gr < 0 ? -gr : (gr >= IH ? 2 * IH - 2 - gr : gr);
                        v[j] = src[(size_t)gr * IW + gc];
                    }
                }
#pragma unroll
                for (int o = 0; o < 8; ++o) {
                    float acc = v[o + 12] * kk[12];
#pragma unroll
                    for (int t = 0; t < 12; ++t)
                        acc = fmaf(v[o + t] + v[o + 24 - t], kk[t], acc);
                    // lanes = consecutive cp within a row -> conflict-free
                    mid[(8 * rb + o) * MSTRIDE + cp] = acc;
                }
            }
        }
        __syncthreads();

        // ---------- phase H: horizontal pass, LDS -> out --------------------
        // task (r, g): row r, output cols c0g+8g..+7; reads mid[r][8g+4+j],
        // bank = (r + 8g + 4 + j)%32 -> exact 2-way (free). Stores: wave
        // covers 8 rows x 128B contiguous per row.
        {
            const float* __restrict__ mrow = &mid[r * MSTRIDE + 8 * g + 4];
            float v[32];
#pragma unroll
            for (int j = 0; j < 32; ++j) v[j] = mrow[j];

            float acc[8];
#pragma unroll
            for (int o = 0; o < 8; ++o) {
                float a = v[o + 12] * kk[12];
#pragma unroll
                for (int t = 0; t < 12; ++t)
                    a = fmaf(v[o + t] + v[o + 24 - t], kk[t], a);
                acc[o] = a;
            }

            float* __restrict__ dst = out + (size_t)z * (IW * IH)
                                    + (size_t)(r0g + r) * IW + c0g + 8 * g;
            *(float4*)(dst + 0) = make_float4(acc[0], acc[1], acc[2], acc[3]);
            *(float4*)(dst + 4) = make_float4(acc[4], acc[5], acc[6], acc[7]);
        }
    }
}

extern "C" void kernel_launch(void* const* d_in, const int* in_sizes, int n_in,
                              void* d_out, int out_size, void* d_ws, size_t ws_size,
                              hipStream_t stream)
{
    const float* x   = (const float*)d_in[0];
    const float* wgt = (const float*)d_in[1];
    float* out = (float*)d_out;

    dim3 grid(IW / TW, IH / TH, ZGRID);   // 8 x 16 x 24 = 3072 blocks
    gauss_blur_sep3_kernel<<<grid, dim3(256), 0, stream>>>(x, wgt, out);
}